// Round 4
// baseline (590.662 us; speedup 1.0000x reference)
//
#include <hip/hip_runtime.h>
#include <hip/hip_bf16.h>

#define NN 50000
#define EE 800000
#define NTILES 782   // ceil(50000/64)
#define NB 391       // ceil(50000/128) buckets of 128 nodes

typedef __bf16 bf16x8 __attribute__((ext_vector_type(8)));
typedef unsigned short us8 __attribute__((ext_vector_type(8)));
typedef float f32x4 __attribute__((ext_vector_type(4)));

__device__ __forceinline__ unsigned short f2bf(float f) {
  unsigned u = __float_as_uint(f);
  u += 0x7FFFu + ((u >> 16) & 1u);           // round-to-nearest-even
  return (unsigned short)(u >> 16);
}
__device__ __forceinline__ float bflo(unsigned u) { return __uint_as_float(u << 16); }
__device__ __forceinline__ float bfhi(unsigned u) { return __uint_as_float(u & 0xFFFF0000u); }
__device__ __forceinline__ float bf2f(unsigned short h) { return __uint_as_float(((unsigned)h) << 16); }
__device__ __forceinline__ float fast_tanh(float x) {
  float e = __expf(2.0f * x);
  return 1.0f - 2.0f / (e + 1.0f);
}

// ---------------- weight pre-pack: W fp32 [3][K][64] -> Wt bf16 [192][K] (col=p*64+c) --------

__global__ __launch_bounds__(256) void k_pack(const float* __restrict__ w0, const float* __restrict__ w1,
                                              const float* __restrict__ w2, const float* __restrict__ w3,
                                              const float* __restrict__ w4, const float* __restrict__ w5,
                                              unsigned short* t0, unsigned short* t1,
                                              unsigned short* t2, unsigned short* t3,
                                              unsigned short* t4, unsigned short* t5) {
  int y = blockIdx.y;
  const float* W = (y == 0) ? w0 : (y == 1) ? w1 : (y == 2) ? w2 : (y == 3) ? w3 : (y == 4) ? w4 : w5;
  unsigned short* T = (y == 0) ? t0 : (y == 1) ? t1 : (y == 2) ? t2 : (y == 3) ? t3 : (y == 4) ? t4 : t5;
  int K = (y < 2) ? 256 : 192;
  int tid = blockIdx.x * 256 + threadIdx.x;
  if (tid >= 192 * K) return;
  int col = tid / K;
  int k = tid - col * K;
  T[tid] = f2bf(W[(col >> 6) * (K * 64) + k * 64 + (col & 63)]);
}

// ---------------- bucketed CSR build ----------------

__global__ __launch_bounds__(256) void k_hist(const int* __restrict__ ei, int* __restrict__ bCnt) {
  __shared__ int h[2 * NB];
  for (int i = threadIdx.x; i < 2 * NB; i += 256) h[i] = 0;
  __syncthreads();
  int base = blockIdx.x * 2048;
#pragma unroll
  for (int j = 0; j < 8; ++j) {
    int e = base + j * 256 + threadIdx.x;
    if (e < EE) {
      int s = ei[e], d = ei[EE + e];
      atomicAdd(&h[d >> 7], 1);
      atomicAdd(&h[NB + (s >> 7)], 1);
    }
  }
  __syncthreads();
  for (int i = threadIdx.x; i < 2 * NB; i += 256) {
    int c = h[i];
    if (c) atomicAdd(&bCnt[i], c);
  }
}

__global__ __launch_bounds__(512) void k_bscan(const int* __restrict__ bCnt,
                                               int* __restrict__ bOff, int* __restrict__ bCur) {
  __shared__ int sd[512];
  int z = blockIdx.x, t = threadIdx.x;
  sd[t] = (t < NB) ? bCnt[z * NB + t] : 0;
  __syncthreads();
  for (int o = 1; o < 512; o <<= 1) {
    int v = (t >= o) ? sd[t - o] : 0;
    __syncthreads();
    sd[t] += v;
    __syncthreads();
  }
  int ex = (t > 0) ? sd[t - 1] : 0;
  if (t < NB) { bOff[z * (NB + 1) + t] = ex; bCur[z * NB + t] = ex; }
  if (t == NB) bOff[z * (NB + 1) + NB] = ex;   // = total = EE
}

__global__ __launch_bounds__(256) void k_scatter(const int* __restrict__ ei,
                                                 int* __restrict__ bCur,
                                                 unsigned* __restrict__ binA,
                                                 unsigned* __restrict__ binB) {
  __shared__ int h[2 * NB];
  for (int i = threadIdx.x; i < 2 * NB; i += 256) h[i] = 0;
  __syncthreads();
  int base = blockIdx.x * 2048;
  int s[8], d[8], la[8], lb[8];
#pragma unroll
  for (int j = 0; j < 8; ++j) {
    int e = base + j * 256 + threadIdx.x;
    d[j] = -1;
    if (e < EE) {
      s[j] = ei[e]; d[j] = ei[EE + e];
      la[j] = atomicAdd(&h[d[j] >> 7], 1);
      lb[j] = atomicAdd(&h[NB + (s[j] >> 7)], 1);
    }
  }
  __syncthreads();
  for (int i = threadIdx.x; i < 2 * NB; i += 256) {
    int c = h[i];
    if (c) h[i] = atomicAdd(&bCur[i], c);
  }
  __syncthreads();
#pragma unroll
  for (int j = 0; j < 8; ++j) {
    if (d[j] >= 0) {
      int pa = h[d[j] >> 7] + la[j];
      binA[pa] = ((unsigned)s[j] << 7) | (unsigned)(d[j] & 127);
      int pb = h[NB + (s[j] >> 7)] + lb[j];
      binB[pb] = ((unsigned)d[j] << 7) | (unsigned)(s[j] & 127);
    }
  }
}

__global__ __launch_bounds__(256) void k_build(const unsigned* __restrict__ binA,
                                               const unsigned* __restrict__ binB,
                                               const int* __restrict__ bOff,
                                               int* __restrict__ rpA, int* __restrict__ rpB,
                                               int* __restrict__ colA, int* __restrict__ colB,
                                               float* __restrict__ dinvA, float* __restrict__ dinvB) {
  int z = blockIdx.y, b = blockIdx.x, t = threadIdx.x;
  const unsigned* bin = z ? binB : binA;
  int* rp = z ? rpB : rpA;
  int* col = z ? colB : colA;
  float* dinv = z ? dinvB : dinvA;

  int e0 = bOff[z * (NB + 1) + b], e1 = bOff[z * (NB + 1) + b + 1];

  __shared__ int cnt[128];
  __shared__ int scn[128];
  __shared__ int cur[128];
  if (t < 128) cnt[t] = 0;
  __syncthreads();
  for (int e = e0 + t; e < e1; e += 256) atomicAdd(&cnt[bin[e] & 127], 1);
  __syncthreads();
  if (t < 128) scn[t] = cnt[t];
  __syncthreads();
  for (int o = 1; o < 128; o <<= 1) {
    int v = (t < 128 && t >= o) ? scn[t - o] : 0;
    __syncthreads();
    if (t < 128) scn[t] += v;
    __syncthreads();
  }
  if (t < 128) {
    int ex = scn[t] - cnt[t];
    cur[t] = ex;
    int node = b * 128 + t;
    if (node <= NN) rp[node] = e0 + ex;
    if (node < NN) dinv[node] = rsqrtf((float)(cnt[t] + 1));
  }
  if (b == 0 && t < 16) col[EE + t] = 0;   // pad for 16-wide tail loads
  __syncthreads();
  for (int e = e0 + t; e < e1; e += 256) {
    unsigned p = bin[e];
    int pos = e0 + atomicAdd(&cur[p & 127], 1);
    col[pos] = (int)(p >> 7);
  }
}

// ---------------- fused 3-power GEMM:  Z = Hin @ [w0|w1|w2]  (M=50000,K,N=192) ----------------
// cols 64..191 of Z are written PRE-SCALED by dinv[row].

template<int K, bool F32IN>
__global__ __launch_bounds__(256) void k_gemm(const void* __restrict__ in0, const void* __restrict__ in1,
                                              const unsigned short* __restrict__ Wt0,
                                              const unsigned short* __restrict__ Wt1,
                                              const float* __restrict__ dinvA, const float* __restrict__ dinvB,
                                              unsigned short* __restrict__ Z0, unsigned short* __restrict__ Z1) {
  constexpr int KS = K / 32;
  constexpr int KP = K + 8;
  __shared__ unsigned short A_lds[64 * KP];
  __shared__ float dvt[64];

  int z = blockIdx.y;
  const void* Ain = z ? in1 : in0;
  const unsigned short* Wt = z ? Wt1 : Wt0;
  const float* dinv = z ? dinvB : dinvA;
  unsigned short* Zo = z ? Z1 : Z0;

  int t = threadIdx.x;
  int lane = t & 63, wv = t >> 6;
  int nloc = lane & 15, quad = lane >> 4;

  // preload all B fragments: single contiguous 16B loads from pre-packed W^T
  bf16x8 b[3][KS];
#pragma unroll
  for (int nt = 0; nt < 3; ++nt) {
    int ncol = wv * 48 + nt * 16 + nloc;                 // 0..191
#pragma unroll
    for (int ks = 0; ks < KS; ++ks)
      b[nt][ks] = *(const bf16x8*)(Wt + (size_t)ncol * K + ks * 32 + quad * 8);
  }

  for (int bm = blockIdx.x; bm < NTILES; bm += gridDim.x) {
    int m0 = bm * 64;
    __syncthreads();
    if (t < 64) dvt[t] = (m0 + t < NN) ? dinv[m0 + t] : 0.f;
#pragma unroll
    for (int it = 0; it < KS; ++it) {
      int c = it * 256 + t;
      int row = c / (K / 8);
      int kc  = c % (K / 8);
      int gr = m0 + row;
      us8 val;
      if (F32IN) {
        float4 v0 = make_float4(0, 0, 0, 0), v1 = make_float4(0, 0, 0, 0);
        if (gr < NN) {
          const float* Af = (const float*)Ain + (size_t)gr * K + kc * 8;
          v0 = *(const float4*)(Af);
          v1 = *(const float4*)(Af + 4);
        }
        val[0] = f2bf(v0.x); val[1] = f2bf(v0.y); val[2] = f2bf(v0.z); val[3] = f2bf(v0.w);
        val[4] = f2bf(v1.x); val[5] = f2bf(v1.y); val[6] = f2bf(v1.z); val[7] = f2bf(v1.w);
      } else {
        if (gr < NN) val = *(const us8*)((const unsigned short*)Ain + (size_t)gr * K + kc * 8);
        else         val = (us8)0;
      }
      *(us8*)(&A_lds[row * KP + kc * 8]) = val;
    }
    __syncthreads();

    f32x4 acc[4][3];
#pragma unroll
    for (int mt = 0; mt < 4; ++mt)
#pragma unroll
      for (int nt = 0; nt < 3; ++nt) acc[mt][nt] = (f32x4){0.f, 0.f, 0.f, 0.f};

#pragma unroll
    for (int ks = 0; ks < KS; ++ks) {
      bf16x8 a[4];
#pragma unroll
      for (int mt = 0; mt < 4; ++mt)
        a[mt] = *(const bf16x8*)(&A_lds[(mt * 16 + nloc) * KP + ks * 32 + quad * 8]);
#pragma unroll
      for (int mt = 0; mt < 4; ++mt)
#pragma unroll
        for (int nt = 0; nt < 3; ++nt)
          acc[mt][nt] = __builtin_amdgcn_mfma_f32_16x16x32_bf16(a[mt], b[nt][ks], acc[mt][nt], 0, 0, 0);
    }

#pragma unroll
    for (int mt = 0; mt < 4; ++mt) {
      int rowb = m0 + mt * 16 + quad * 4;
#pragma unroll
      for (int nt = 0; nt < 3; ++nt) {
        int colg = wv * 48 + nt * 16 + nloc;
        bool sc = (wv * 48 + nt * 16) >= 64;     // whole 16-col block on one side
#pragma unroll
        for (int r = 0; r < 4; ++r) {
          int rr = rowb + r;
          float scale = sc ? dvt[mt * 16 + quad * 4 + r] : 1.0f;
          if (rr < NN) Zo[(size_t)rr * 192 + colg] = f2bf(acc[mt][nt][r] * scale);
        }
      }
    }
  }
}

// ---------------- prop1: T = Ahat * Z[:,64:192] (pre-scaled rows); half-wave = 2 edges/instr --

__global__ __launch_bounds__(256) void k_prop1(const unsigned short* __restrict__ Z0,
                                               const unsigned short* __restrict__ Z1,
                                               unsigned short* __restrict__ T0,
                                               unsigned short* __restrict__ T1,
                                               const int* __restrict__ rpA, const int* __restrict__ rpB,
                                               const int* __restrict__ colA, const int* __restrict__ colB,
                                               const float* __restrict__ dinvA, const float* __restrict__ dinvB) {
  int z = blockIdx.y;
  const unsigned short* Z = z ? Z1 : Z0;
  unsigned short* T = z ? T1 : T0;
  const int* rp = z ? rpB : rpA;
  const int* col = z ? colB : colA;
  const float* dinv = z ? dinvB : dinvA;

  int wv = threadIdx.x >> 6, lane = threadIdx.x & 63;
  int h = lane >> 5, l = lane & 31;
  int v = __builtin_amdgcn_readfirstlane(blockIdx.x * 4 + wv);

  int e0 = rp[v], e1 = rp[v + 1];
  float dv = dinv[v];

  float a0 = 0, a1 = 0, a2 = 0, a3 = 0;   // Z cols 64+4l .. 67+4l

  int e = e0;
  if (e + 16 <= e1) {
    int idx[8];
#pragma unroll
    for (int j = 0; j < 8; ++j) idx[j] = col[e + 2 * j + h];
    e += 16;
    while (e + 16 <= e1) {
      int nidx[8];
#pragma unroll
      for (int j = 0; j < 8; ++j) nidx[j] = col[e + 2 * j + h];
      uint2 pp[8];
#pragma unroll
      for (int j = 0; j < 8; ++j) pp[j] = *(const uint2*)(Z + (size_t)idx[j] * 192 + 64 + l * 4);
#pragma unroll
      for (int j = 0; j < 8; ++j) {
        a0 += bflo(pp[j].x); a1 += bfhi(pp[j].x);
        a2 += bflo(pp[j].y); a3 += bfhi(pp[j].y);
      }
#pragma unroll
      for (int j = 0; j < 8; ++j) idx[j] = nidx[j];
      e += 16;
    }
    uint2 pp[8];
#pragma unroll
    for (int j = 0; j < 8; ++j) pp[j] = *(const uint2*)(Z + (size_t)idx[j] * 192 + 64 + l * 4);
#pragma unroll
    for (int j = 0; j < 8; ++j) {
      a0 += bflo(pp[j].x); a1 += bfhi(pp[j].x);
      a2 += bflo(pp[j].y); a3 += bfhi(pp[j].y);
    }
  }
  int r = e1 - e;
  if (r > 0) {
    int idx[8];
#pragma unroll
    for (int j = 0; j < 8; ++j) idx[j] = col[e + 2 * j + h];   // padded: safe past e1
    uint2 pp[8];
#pragma unroll
    for (int j = 0; j < 8; ++j) pp[j] = *(const uint2*)(Z + (size_t)idx[j] * 192 + 64 + l * 4);
#pragma unroll
    for (int j = 0; j < 8; ++j) if (2 * j + h < r) {
      a0 += bflo(pp[j].x); a1 += bfhi(pp[j].x);
      a2 += bflo(pp[j].y); a3 += bfhi(pp[j].y);
    }
  }

  a0 += __shfl_xor(a0, 32); a1 += __shfl_xor(a1, 32);
  a2 += __shfl_xor(a2, 32); a3 += __shfl_xor(a3, 32);

  uint2 sv = *(const uint2*)(Z + (size_t)v * 192 + 64 + l * 4);   // self (pre-scaled)
  a0 += bflo(sv.x); a1 += bfhi(sv.x); a2 += bflo(sv.y); a3 += bfhi(sv.y);

  float sc = dv * (l >= 16 ? dv : 1.0f);   // T cols >=64 carry extra dv for next gather
  if (h == 0) {
    uint2 o;
    o.x = (unsigned)f2bf(a0 * sc) | ((unsigned)f2bf(a1 * sc) << 16);
    o.y = (unsigned)f2bf(a2 * sc) | ((unsigned)f2bf(a3 * sc) << 16);
    *(uint2*)(T + (size_t)v * 128 + l * 4) = o;
  }
}

// ---------------- combine: U = Ahat * T[:,64:128]; out = tanh([Z0+b0 | T0+b1 | U+b2]) --------

template<bool FINAL>
__global__ __launch_bounds__(256) void k_combine(const unsigned short* __restrict__ Z0,
                                                 const unsigned short* __restrict__ Z1,
                                                 const unsigned short* __restrict__ T0,
                                                 const unsigned short* __restrict__ T1,
                                                 unsigned short* __restrict__ H0,
                                                 unsigned short* __restrict__ H1,
                                                 float* __restrict__ out,
                                                 const float* __restrict__ bia0, const float* __restrict__ bia1,
                                                 const int* __restrict__ rpA, const int* __restrict__ rpB,
                                                 const int* __restrict__ colA, const int* __restrict__ colB,
                                                 const float* __restrict__ dinvA, const float* __restrict__ dinvB) {
  int z = blockIdx.y;
  const unsigned short* Z = z ? Z1 : Z0;
  const unsigned short* T = z ? T1 : T0;
  unsigned short* H = z ? H1 : H0;
  const float* bias = z ? bia1 : bia0;
  const int* rp = z ? rpB : rpA;
  const int* col = z ? colB : colA;
  const float* dinv = z ? dinvB : dinvA;

  int wv = threadIdx.x >> 6, lane = threadIdx.x & 63;
  int h = lane >> 5, l = lane & 31;
  int v = __builtin_amdgcn_readfirstlane(blockIdx.x * 4 + wv);

  int e0 = rp[v], e1 = rp[v + 1];
  float dv = dinv[v];

  float u0 = 0, u1 = 0;    // prescaled-T cols 64+2l, 65+2l

  int e = e0;
  if (e + 16 <= e1) {
    int idx[8];
#pragma unroll
    for (int j = 0; j < 8; ++j) idx[j] = col[e + 2 * j + h];
    e += 16;
    while (e + 16 <= e1) {
      int nidx[8];
#pragma unroll
      for (int j = 0; j < 8; ++j) nidx[j] = col[e + 2 * j + h];
      unsigned pp[8];
#pragma unroll
      for (int j = 0; j < 8; ++j) pp[j] = *(const unsigned*)(T + (size_t)idx[j] * 128 + 64 + l * 2);
#pragma unroll
      for (int j = 0; j < 8; ++j) { u0 += bflo(pp[j]); u1 += bfhi(pp[j]); }
#pragma unroll
      for (int j = 0; j < 8; ++j) idx[j] = nidx[j];
      e += 16;
    }
    unsigned pp[8];
#pragma unroll
    for (int j = 0; j < 8; ++j) pp[j] = *(const unsigned*)(T + (size_t)idx[j] * 128 + 64 + l * 2);
#pragma unroll
    for (int j = 0; j < 8; ++j) { u0 += bflo(pp[j]); u1 += bfhi(pp[j]); }
  }
  int r = e1 - e;
  if (r > 0) {
    int idx[8];
#pragma unroll
    for (int j = 0; j < 8; ++j) idx[j] = col[e + 2 * j + h];   // padded: safe past e1
    unsigned pp[8];
#pragma unroll
    for (int j = 0; j < 8; ++j) pp[j] = *(const unsigned*)(T + (size_t)idx[j] * 128 + 64 + l * 2);
#pragma unroll
    for (int j = 0; j < 8; ++j) if (2 * j + h < r) { u0 += bflo(pp[j]); u1 += bfhi(pp[j]); }
  }

  u0 += __shfl_xor(u0, 32);
  u1 += __shfl_xor(u1, 32);
  // redistribute: lane k wants U col k, held as comp (k&1) of lane (k>>1)
  float ua = __shfl(u0, lane >> 1);
  float ub = __shfl(u1, lane >> 1);
  float u = (lane & 1) ? ub : ua;

  const unsigned short* Trow = T + (size_t)v * 128;
  u += bf2f(Trow[64 + lane]);     // self (prescaled = dv*T[v])
  u *= dv;

  float p0 = fast_tanh(bf2f(Z[(size_t)v * 192 + lane]) + bias[lane]);
  float p1 = fast_tanh(bf2f(Trow[lane]) + bias[64 + lane]);
  float p2 = fast_tanh(u + bias[128 + lane]);

  if (FINAL) {
    float* o = out + (size_t)z * NN * 192 + (size_t)v * 192;
    o[lane] = p0; o[lane + 64] = p1; o[lane + 128] = p2;
  } else {
    unsigned short* hh = H + (size_t)v * 192;
    hh[lane] = f2bf(p0); hh[lane + 64] = f2bf(p1); hh[lane + 128] = f2bf(p2);
  }
}

// ---------------- host ----------------

extern "C" void kernel_launch(void* const* d_in, const int* in_sizes, int n_in,
                              void* d_out, int out_size, void* d_ws, size_t ws_size,
                              hipStream_t stream) {
  const float* x  = (const float*)d_in[0];
  const int* ei   = (const int*)d_in[1];
  const float* wout1 = (const float*)d_in[2];
  const float* bout1 = (const float*)d_in[3];
  const float* wout2 = (const float*)d_in[4];
  const float* bout2 = (const float*)d_in[5];
  const float* wout3 = (const float*)d_in[6];
  const float* bout3 = (const float*)d_in[7];
  const float* win1  = (const float*)d_in[8];
  const float* bin1  = (const float*)d_in[9];
  const float* win2  = (const float*)d_in[10];
  const float* bin2  = (const float*)d_in[11];
  const float* win3  = (const float*)d_in[12];
  const float* bin3  = (const float*)d_in[13];
  float* out = (float*)d_out;

  char* p = (char*)d_ws;
  auto alloc = [&](size_t bytes) { char* r = p; p += (bytes + 255) & ~(size_t)255; return r; };
  int* rpA   = (int*)alloc((size_t)(NN + 1) * 4);
  int* rpB   = (int*)alloc((size_t)(NN + 1) * 4);
  int* colA  = (int*)alloc((size_t)(EE + 16) * 4);
  int* colB  = (int*)alloc((size_t)(EE + 16) * 4);
  float* dinvA = (float*)alloc((size_t)NN * 4);
  float* dinvB = (float*)alloc((size_t)NN * 4);
  int* bCnt  = (int*)alloc((size_t)2 * NB * 4);
  int* bOff  = (int*)alloc((size_t)2 * (NB + 1) * 4);
  int* bCur  = (int*)alloc((size_t)2 * NB * 4);
  unsigned short* wt0 = (unsigned short*)alloc((size_t)192 * 256 * 2);
  unsigned short* wt1 = (unsigned short*)alloc((size_t)192 * 256 * 2);
  unsigned short* wt2 = (unsigned short*)alloc((size_t)192 * 192 * 2);
  unsigned short* wt3 = (unsigned short*)alloc((size_t)192 * 192 * 2);
  unsigned short* wt4 = (unsigned short*)alloc((size_t)192 * 192 * 2);
  unsigned short* wt5 = (unsigned short*)alloc((size_t)192 * 192 * 2);
  unsigned short* Z0 = (unsigned short*)alloc((size_t)NN * 192 * 2);
  unsigned short* Z1 = (unsigned short*)alloc((size_t)NN * 192 * 2);
  unsigned short* T0 = (unsigned short*)alloc((size_t)NN * 128 * 2);
  unsigned short* T1 = (unsigned short*)alloc((size_t)NN * 128 * 2);
  unsigned short* H0 = (unsigned short*)alloc((size_t)NN * 192 * 2);
  unsigned short* H1 = (unsigned short*)alloc((size_t)NN * 192 * 2);

  unsigned* binA = (unsigned*)Z0;   // alias: bins dead before Z written
  unsigned* binB = (unsigned*)Z1;

  // ---- weight pre-pack + graph build ----
  k_pack<<<dim3(192, 6), 256, 0, stream>>>(wout1, win1, wout2, win2, wout3, win3,
                                           wt0, wt1, wt2, wt3, wt4, wt5);
  hipMemsetAsync(bCnt, 0, (size_t)2 * NB * 4, stream);
  k_hist<<<391, 256, 0, stream>>>(ei, bCnt);
  k_bscan<<<2, 512, 0, stream>>>(bCnt, bOff, bCur);
  k_scatter<<<391, 256, 0, stream>>>(ei, bCur, binA, binB);
  k_build<<<dim3(NB, 2), 256, 0, stream>>>(binA, binB, bOff, rpA, rpB, colA, colB, dinvA, dinvB);

  dim3 gGemm(391, 2);     // 2 M-tiles per block, ~3 blocks/CU
  dim3 gProp(12500, 2);   // 4 nodes (waves) per block

  // ---- layer 1 (K=256, fp32 input x shared by both encoders) ----
  k_gemm<256, true><<<gGemm, 256, 0, stream>>>(x, x, wt0, wt1, dinvA, dinvB, Z0, Z1);
  k_prop1<<<gProp, 256, 0, stream>>>(Z0, Z1, T0, T1, rpA, rpB, colA, colB, dinvA, dinvB);
  k_combine<false><<<gProp, 256, 0, stream>>>(Z0, Z1, T0, T1, H0, H1, nullptr, bout1, bin1,
                                              rpA, rpB, colA, colB, dinvA, dinvB);
  // ---- layer 2 (K=192) ----
  k_gemm<192, false><<<gGemm, 256, 0, stream>>>(H0, H1, wt2, wt3, dinvA, dinvB, Z0, Z1);
  k_prop1<<<gProp, 256, 0, stream>>>(Z0, Z1, T0, T1, rpA, rpB, colA, colB, dinvA, dinvB);
  k_combine<false><<<gProp, 256, 0, stream>>>(Z0, Z1, T0, T1, H0, H1, nullptr, bout2, bin2,
                                              rpA, rpB, colA, colB, dinvA, dinvB);
  // ---- layer 3 (K=192, writes fp32 d_out) ----
  k_gemm<192, false><<<gGemm, 256, 0, stream>>>(H0, H1, wt4, wt5, dinvA, dinvB, Z0, Z1);
  k_prop1<<<gProp, 256, 0, stream>>>(Z0, Z1, T0, T1, rpA, rpB, colA, colB, dinvA, dinvB);
  k_combine<true><<<gProp, 256, 0, stream>>>(Z0, Z1, T0, T1, H0, H1, out, bout3, bin3,
                                             rpA, rpB, colA, colB, dinvA, dinvB);
}

// Round 5
// 574.034 us; speedup vs baseline: 1.0290x; 1.0290x over previous
//
#include <hip/hip_runtime.h>
#include <hip/hip_bf16.h>

#define NN 50000
#define MPAD 50048   // 782 * 64
#define EE 800000
#define NTILES 782   // MPAD/64
#define NB 391       // ceil(50000/128) buckets of 128 nodes

typedef __bf16 bf16x8 __attribute__((ext_vector_type(8)));
typedef unsigned short us8 __attribute__((ext_vector_type(8)));
typedef float f32x4 __attribute__((ext_vector_type(4)));

__device__ __forceinline__ unsigned short f2bf(float f) {
  unsigned u = __float_as_uint(f);
  u += 0x7FFFu + ((u >> 16) & 1u);           // round-to-nearest-even
  return (unsigned short)(u >> 16);
}
__device__ __forceinline__ float bflo(unsigned u) { return __uint_as_float(u << 16); }
__device__ __forceinline__ float bfhi(unsigned u) { return __uint_as_float(u & 0xFFFF0000u); }
__device__ __forceinline__ float bf2f(unsigned short h) { return __uint_as_float(((unsigned)h) << 16); }
__device__ __forceinline__ float fast_tanh(float x) {
  float e = __expf(2.0f * x);
  return 1.0f - 2.0f / (e + 1.0f);
}

// async global(16B) -> LDS; LDS dest is wave-uniform base + lane*16
__device__ __forceinline__ void gload_lds16(const unsigned short* g, unsigned short* l) {
  __builtin_amdgcn_global_load_lds(
      (const __attribute__((address_space(1))) unsigned*)g,
      (__attribute__((address_space(3))) unsigned*)l, 16, 0, 0);
}

// ---------------- x fp32 -> bf16 (padded rows zeroed) ----------------

__global__ __launch_bounds__(256) void k_xcast(const float* __restrict__ x, unsigned short* __restrict__ Xb) {
  int c = blockIdx.x * 256 + threadIdx.x;        // 8-elem chunk; grid = MPAD*256/8/256 = 6256
  size_t base = (size_t)c * 8;
  us8 v;
  if (base < (size_t)NN * 256) {
    const float* xp = x + base;
    float4 v0 = *(const float4*)xp;
    float4 v1 = *(const float4*)(xp + 4);
    v[0] = f2bf(v0.x); v[1] = f2bf(v0.y); v[2] = f2bf(v0.z); v[3] = f2bf(v0.w);
    v[4] = f2bf(v1.x); v[5] = f2bf(v1.y); v[6] = f2bf(v1.z); v[7] = f2bf(v1.w);
  } else {
    v = (us8)0;
  }
  *(us8*)(Xb + base) = v;
}

// ---------------- weight pre-pack: W fp32 [3][K][64] -> Wt bf16 [192][K] ----------------

__global__ __launch_bounds__(256) void k_pack(const float* __restrict__ w0, const float* __restrict__ w1,
                                              const float* __restrict__ w2, const float* __restrict__ w3,
                                              const float* __restrict__ w4, const float* __restrict__ w5,
                                              unsigned short* t0, unsigned short* t1,
                                              unsigned short* t2, unsigned short* t3,
                                              unsigned short* t4, unsigned short* t5) {
  int y = blockIdx.y;
  const float* W = (y == 0) ? w0 : (y == 1) ? w1 : (y == 2) ? w2 : (y == 3) ? w3 : (y == 4) ? w4 : w5;
  unsigned short* T = (y == 0) ? t0 : (y == 1) ? t1 : (y == 2) ? t2 : (y == 3) ? t3 : (y == 4) ? t4 : t5;
  int K = (y < 2) ? 256 : 192;
  int tid = blockIdx.x * 256 + threadIdx.x;
  if (tid >= 192 * K) return;
  int col = tid / K;
  int k = tid - col * K;
  T[tid] = f2bf(W[(col >> 6) * (K * 64) + k * 64 + (col & 63)]);
}

// ---------------- bucketed CSR build ----------------

__global__ __launch_bounds__(256) void k_hist(const int* __restrict__ ei, int* __restrict__ bCnt) {
  __shared__ int h[2 * NB];
  for (int i = threadIdx.x; i < 2 * NB; i += 256) h[i] = 0;
  __syncthreads();
  int base = blockIdx.x * 2048;
#pragma unroll
  for (int j = 0; j < 8; ++j) {
    int e = base + j * 256 + threadIdx.x;
    if (e < EE) {
      int s = ei[e], d = ei[EE + e];
      atomicAdd(&h[d >> 7], 1);
      atomicAdd(&h[NB + (s >> 7)], 1);
    }
  }
  __syncthreads();
  for (int i = threadIdx.x; i < 2 * NB; i += 256) {
    int c = h[i];
    if (c) atomicAdd(&bCnt[i], c);
  }
}

__global__ __launch_bounds__(512) void k_bscan(const int* __restrict__ bCnt,
                                               int* __restrict__ bOff, int* __restrict__ bCur) {
  __shared__ int sd[512];
  int z = blockIdx.x, t = threadIdx.x;
  sd[t] = (t < NB) ? bCnt[z * NB + t] : 0;
  __syncthreads();
  for (int o = 1; o < 512; o <<= 1) {
    int v = (t >= o) ? sd[t - o] : 0;
    __syncthreads();
    sd[t] += v;
    __syncthreads();
  }
  int ex = (t > 0) ? sd[t - 1] : 0;
  if (t < NB) { bOff[z * (NB + 1) + t] = ex; bCur[z * NB + t] = ex; }
  if (t == NB) bOff[z * (NB + 1) + NB] = ex;   // = total = EE
}

__global__ __launch_bounds__(256) void k_scatter(const int* __restrict__ ei,
                                                 int* __restrict__ bCur,
                                                 unsigned* __restrict__ binA,
                                                 unsigned* __restrict__ binB) {
  __shared__ int h[2 * NB];
  for (int i = threadIdx.x; i < 2 * NB; i += 256) h[i] = 0;
  __syncthreads();
  int base = blockIdx.x * 2048;
  int s[8], d[8], la[8], lb[8];
#pragma unroll
  for (int j = 0; j < 8; ++j) {
    int e = base + j * 256 + threadIdx.x;
    d[j] = -1;
    if (e < EE) {
      s[j] = ei[e]; d[j] = ei[EE + e];
      la[j] = atomicAdd(&h[d[j] >> 7], 1);
      lb[j] = atomicAdd(&h[NB + (s[j] >> 7)], 1);
    }
  }
  __syncthreads();
  for (int i = threadIdx.x; i < 2 * NB; i += 256) {
    int c = h[i];
    if (c) h[i] = atomicAdd(&bCur[i], c);
  }
  __syncthreads();
#pragma unroll
  for (int j = 0; j < 8; ++j) {
    if (d[j] >= 0) {
      int pa = h[d[j] >> 7] + la[j];
      binA[pa] = ((unsigned)s[j] << 7) | (unsigned)(d[j] & 127);
      int pb = h[NB + (s[j] >> 7)] + lb[j];
      binB[pb] = ((unsigned)d[j] << 7) | (unsigned)(s[j] & 127);
    }
  }
}

__global__ __launch_bounds__(256) void k_build(const unsigned* __restrict__ binA,
                                               const unsigned* __restrict__ binB,
                                               const int* __restrict__ bOff,
                                               int* __restrict__ rpA, int* __restrict__ rpB,
                                               int* __restrict__ colA, int* __restrict__ colB,
                                               float* __restrict__ dinvA, float* __restrict__ dinvB) {
  int z = blockIdx.y, b = blockIdx.x, t = threadIdx.x;
  const unsigned* bin = z ? binB : binA;
  int* rp = z ? rpB : rpA;
  int* col = z ? colB : colA;
  float* dinv = z ? dinvB : dinvA;

  int e0 = bOff[z * (NB + 1) + b], e1 = bOff[z * (NB + 1) + b + 1];

  __shared__ int cnt[128];
  __shared__ int scn[128];
  __shared__ int cur[128];
  if (t < 128) cnt[t] = 0;
  __syncthreads();
  for (int e = e0 + t; e < e1; e += 256) atomicAdd(&cnt[bin[e] & 127], 1);
  __syncthreads();
  if (t < 128) scn[t] = cnt[t];
  __syncthreads();
  for (int o = 1; o < 128; o <<= 1) {
    int v = (t < 128 && t >= o) ? scn[t - o] : 0;
    __syncthreads();
    if (t < 128) scn[t] += v;
    __syncthreads();
  }
  if (t < 128) {
    int ex = scn[t] - cnt[t];
    cur[t] = ex;
    int node = b * 128 + t;
    if (node <= NN) rp[node] = e0 + ex;
    if (node < NN) dinv[node] = rsqrtf((float)(cnt[t] + 1));
  }
  if (b == 0 && t < 16) col[EE + t] = 0;   // pad for 16-wide tail loads
  __syncthreads();
  for (int e = e0 + t; e < e1; e += 256) {
    unsigned p = bin[e];
    int pos = e0 + atomicAdd(&cur[p & 127], 1);
    col[pos] = (int)(p >> 7);
  }
}

// ---------------- fused 3-power GEMM:  Z = A @ [w0|w1|w2]  (M=MPAD,K,N=192) ----------------
// A staged via global_load_lds (16B), XOR chunk swizzle breaks bank conflicts.
// Z cols 64..191 written PRE-SCALED by dinv[row].

template<int K>
__global__ __launch_bounds__(256) void k_gemm(const unsigned short* __restrict__ in0,
                                              const unsigned short* __restrict__ in1,
                                              const unsigned short* __restrict__ Wt0,
                                              const unsigned short* __restrict__ Wt1,
                                              const float* __restrict__ dinvA, const float* __restrict__ dinvB,
                                              unsigned short* __restrict__ Z0, unsigned short* __restrict__ Z1) {
  constexpr int KC = K / 8;          // 16B chunks per row
  constexpr int KS = K / 32;
  __shared__ unsigned short A_lds[64 * K];   // unpadded (global_load_lds constraint)
  __shared__ float dvt[64];

  int z = blockIdx.y;
  const unsigned short* Ain = z ? in1 : in0;
  const unsigned short* Wt = z ? Wt1 : Wt0;
  const float* dinv = z ? dinvB : dinvA;
  unsigned short* Zo = z ? Z1 : Z0;

  int t = threadIdx.x;
  int lane = t & 63, wv = t >> 6;
  int nloc = lane & 15, quad = lane >> 4;

  // B fragments: contiguous 16B loads from pre-packed W^T
  bf16x8 b[3][KS];
#pragma unroll
  for (int nt = 0; nt < 3; ++nt) {
    int ncol = wv * 48 + nt * 16 + nloc;                 // 0..191
#pragma unroll
    for (int ks = 0; ks < KS; ++ks)
      b[nt][ks] = *(const bf16x8*)(Wt + (size_t)ncol * K + ks * 32 + quad * 8);
  }

  for (int bm = blockIdx.x; bm < NTILES; bm += gridDim.x) {
    int m0 = bm * 64;
    __syncthreads();                        // LDS reuse guard
    if (t < 64) dvt[t] = (m0 + t < NN) ? dinv[m0 + t] : 0.f;
    // stage 64 x K tile: slot s holds global chunk (row, kc_sw ^ (row&7))
#pragma unroll
    for (int it = 0; it < KC / 4; ++it) {
      int s = it * 256 + t;
      int row = s / KC;
      int kc_sw = s - row * KC;
      int kc_g = kc_sw ^ (row & 7);
      gload_lds16(Ain + (size_t)(m0 + row) * K + kc_g * 8, &A_lds[s * 8]);
    }
    __syncthreads();                        // drains vmcnt

    f32x4 acc[4][3];
#pragma unroll
    for (int mt = 0; mt < 4; ++mt)
#pragma unroll
      for (int nt = 0; nt < 3; ++nt) acc[mt][nt] = (f32x4){0.f, 0.f, 0.f, 0.f};

#pragma unroll
    for (int ks = 0; ks < KS; ++ks) {
      bf16x8 a[4];
#pragma unroll
      for (int mt = 0; mt < 4; ++mt) {
        int r = mt * 16 + nloc;
        int kc = (ks * 4 + quad) ^ (r & 7);
        a[mt] = *(const bf16x8*)(&A_lds[r * K + kc * 8]);
      }
#pragma unroll
      for (int mt = 0; mt < 4; ++mt)
#pragma unroll
        for (int nt = 0; nt < 3; ++nt)
          acc[mt][nt] = __builtin_amdgcn_mfma_f32_16x16x32_bf16(a[mt], b[nt][ks], acc[mt][nt], 0, 0, 0);
    }

#pragma unroll
    for (int mt = 0; mt < 4; ++mt) {
      int rowb = m0 + mt * 16 + quad * 4;
#pragma unroll
      for (int nt = 0; nt < 3; ++nt) {
        int colg = wv * 48 + nt * 16 + nloc;
        bool sc = (wv * 48 + nt * 16) >= 64;     // whole 16-col block on one side
#pragma unroll
        for (int r = 0; r < 4; ++r) {
          int rr = rowb + r;
          float scale = sc ? dvt[mt * 16 + quad * 4 + r] : 1.0f;
          if (rr < NN) Zo[(size_t)rr * 192 + colg] = f2bf(acc[mt][nt][r] * scale);
        }
      }
    }
  }
}

// ---------------- prop1: T = Ahat * Z[:,64:192] (pre-scaled rows); half-wave = 2 edges/instr --

__global__ __launch_bounds__(256) void k_prop1(const unsigned short* __restrict__ Z0,
                                               const unsigned short* __restrict__ Z1,
                                               unsigned short* __restrict__ T0,
                                               unsigned short* __restrict__ T1,
                                               const int* __restrict__ rpA, const int* __restrict__ rpB,
                                               const int* __restrict__ colA, const int* __restrict__ colB,
                                               const float* __restrict__ dinvA, const float* __restrict__ dinvB) {
  int z = blockIdx.y;
  const unsigned short* Z = z ? Z1 : Z0;
  unsigned short* T = z ? T1 : T0;
  const int* rp = z ? rpB : rpA;
  const int* col = z ? colB : colA;
  const float* dinv = z ? dinvB : dinvA;

  int wv = threadIdx.x >> 6, lane = threadIdx.x & 63;
  int h = lane >> 5, l = lane & 31;
  int v = __builtin_amdgcn_readfirstlane(blockIdx.x * 4 + wv);

  int e0 = rp[v], e1 = rp[v + 1];
  float dv = dinv[v];

  float a0 = 0, a1 = 0, a2 = 0, a3 = 0;   // Z cols 64+4l .. 67+4l

  int e = e0;
  if (e + 16 <= e1) {
    int idx[8];
#pragma unroll
    for (int j = 0; j < 8; ++j) idx[j] = col[e + 2 * j + h];
    e += 16;
    while (e + 16 <= e1) {
      int nidx[8];
#pragma unroll
      for (int j = 0; j < 8; ++j) nidx[j] = col[e + 2 * j + h];
      uint2 pp[8];
#pragma unroll
      for (int j = 0; j < 8; ++j) pp[j] = *(const uint2*)(Z + (size_t)idx[j] * 192 + 64 + l * 4);
#pragma unroll
      for (int j = 0; j < 8; ++j) {
        a0 += bflo(pp[j].x); a1 += bfhi(pp[j].x);
        a2 += bflo(pp[j].y); a3 += bfhi(pp[j].y);
      }
#pragma unroll
      for (int j = 0; j < 8; ++j) idx[j] = nidx[j];
      e += 16;
    }
    uint2 pp[8];
#pragma unroll
    for (int j = 0; j < 8; ++j) pp[j] = *(const uint2*)(Z + (size_t)idx[j] * 192 + 64 + l * 4);
#pragma unroll
    for (int j = 0; j < 8; ++j) {
      a0 += bflo(pp[j].x); a1 += bfhi(pp[j].x);
      a2 += bflo(pp[j].y); a3 += bfhi(pp[j].y);
    }
  }
  int r = e1 - e;
  if (r > 0) {
    int idx[8];
#pragma unroll
    for (int j = 0; j < 8; ++j) idx[j] = col[e + 2 * j + h];   // padded: safe past e1
    uint2 pp[8];
#pragma unroll
    for (int j = 0; j < 8; ++j) pp[j] = *(const uint2*)(Z + (size_t)idx[j] * 192 + 64 + l * 4);
#pragma unroll
    for (int j = 0; j < 8; ++j) if (2 * j + h < r) {
      a0 += bflo(pp[j].x); a1 += bfhi(pp[j].x);
      a2 += bflo(pp[j].y); a3 += bfhi(pp[j].y);
    }
  }

  a0 += __shfl_xor(a0, 32); a1 += __shfl_xor(a1, 32);
  a2 += __shfl_xor(a2, 32); a3 += __shfl_xor(a3, 32);

  uint2 sv = *(const uint2*)(Z + (size_t)v * 192 + 64 + l * 4);   // self (pre-scaled)
  a0 += bflo(sv.x); a1 += bfhi(sv.x); a2 += bflo(sv.y); a3 += bfhi(sv.y);

  float sc = dv * (l >= 16 ? dv : 1.0f);   // T cols >=64 carry extra dv for next gather
  if (h == 0) {
    uint2 o;
    o.x = (unsigned)f2bf(a0 * sc) | ((unsigned)f2bf(a1 * sc) << 16);
    o.y = (unsigned)f2bf(a2 * sc) | ((unsigned)f2bf(a3 * sc) << 16);
    *(uint2*)(T + (size_t)v * 128 + l * 4) = o;
  }
}

// ---------------- combine: U = Ahat * T[:,64:128]; out = tanh([Z0+b0 | T0+b1 | U+b2]) --------

template<bool FINAL>
__global__ __launch_bounds__(256) void k_combine(const unsigned short* __restrict__ Z0,
                                                 const unsigned short* __restrict__ Z1,
                                                 const unsigned short* __restrict__ T0,
                                                 const unsigned short* __restrict__ T1,
                                                 unsigned short* __restrict__ H0,
                                                 unsigned short* __restrict__ H1,
                                                 float* __restrict__ out,
                                                 const float* __restrict__ bia0, const float* __restrict__ bia1,
                                                 const int* __restrict__ rpA, const int* __restrict__ rpB,
                                                 const int* __restrict__ colA, const int* __restrict__ colB,
                                                 const float* __restrict__ dinvA, const float* __restrict__ dinvB) {
  int z = blockIdx.y;
  const unsigned short* Z = z ? Z1 : Z0;
  const unsigned short* T = z ? T1 : T0;
  unsigned short* H = z ? H1 : H0;
  const float* bias = z ? bia1 : bia0;
  const int* rp = z ? rpB : rpA;
  const int* col = z ? colB : colA;
  const float* dinv = z ? dinvB : dinvA;

  int wv = threadIdx.x >> 6, lane = threadIdx.x & 63;
  int h = lane >> 5, l = lane & 31;
  int v = __builtin_amdgcn_readfirstlane(blockIdx.x * 4 + wv);

  int e0 = rp[v], e1 = rp[v + 1];
  float dv = dinv[v];

  float u0 = 0, u1 = 0;    // prescaled-T cols 64+2l, 65+2l

  int e = e0;
  if (e + 16 <= e1) {
    int idx[8];
#pragma unroll
    for (int j = 0; j < 8; ++j) idx[j] = col[e + 2 * j + h];
    e += 16;
    while (e + 16 <= e1) {
      int nidx[8];
#pragma unroll
      for (int j = 0; j < 8; ++j) nidx[j] = col[e + 2 * j + h];
      unsigned pp[8];
#pragma unroll
      for (int j = 0; j < 8; ++j) pp[j] = *(const unsigned*)(T + (size_t)idx[j] * 128 + 64 + l * 2);
#pragma unroll
      for (int j = 0; j < 8; ++j) { u0 += bflo(pp[j]); u1 += bfhi(pp[j]); }
#pragma unroll
      for (int j = 0; j < 8; ++j) idx[j] = nidx[j];
      e += 16;
    }
    unsigned pp[8];
#pragma unroll
    for (int j = 0; j < 8; ++j) pp[j] = *(const unsigned*)(T + (size_t)idx[j] * 128 + 64 + l * 2);
#pragma unroll
    for (int j = 0; j < 8; ++j) { u0 += bflo(pp[j]); u1 += bfhi(pp[j]); }
  }
  int r = e1 - e;
  if (r > 0) {
    int idx[8];
#pragma unroll
    for (int j = 0; j < 8; ++j) idx[j] = col[e + 2 * j + h];   // padded: safe past e1
    unsigned pp[8];
#pragma unroll
    for (int j = 0; j < 8; ++j) pp[j] = *(const unsigned*)(T + (size_t)idx[j] * 128 + 64 + l * 2);
#pragma unroll
    for (int j = 0; j < 8; ++j) if (2 * j + h < r) { u0 += bflo(pp[j]); u1 += bfhi(pp[j]); }
  }

  u0 += __shfl_xor(u0, 32);
  u1 += __shfl_xor(u1, 32);
  // redistribute: lane k wants U col k, held as comp (k&1) of lane (k>>1)
  float ua = __shfl(u0, lane >> 1);
  float ub = __shfl(u1, lane >> 1);
  float u = (lane & 1) ? ub : ua;

  const unsigned short* Trow = T + (size_t)v * 128;
  u += bf2f(Trow[64 + lane]);     // self (prescaled = dv*T[v])
  u *= dv;

  float p0 = fast_tanh(bf2f(Z[(size_t)v * 192 + lane]) + bias[lane]);
  float p1 = fast_tanh(bf2f(Trow[lane]) + bias[64 + lane]);
  float p2 = fast_tanh(u + bias[128 + lane]);

  if (FINAL) {
    float* o = out + (size_t)z * NN * 192 + (size_t)v * 192;
    o[lane] = p0; o[lane + 64] = p1; o[lane + 128] = p2;
  } else {
    unsigned short* hh = H + (size_t)v * 192;
    hh[lane] = f2bf(p0); hh[lane + 64] = f2bf(p1); hh[lane + 128] = f2bf(p2);
  }
}

// ---------------- host ----------------

extern "C" void kernel_launch(void* const* d_in, const int* in_sizes, int n_in,
                              void* d_out, int out_size, void* d_ws, size_t ws_size,
                              hipStream_t stream) {
  const float* x  = (const float*)d_in[0];
  const int* ei   = (const int*)d_in[1];
  const float* wout1 = (const float*)d_in[2];
  const float* bout1 = (const float*)d_in[3];
  const float* wout2 = (const float*)d_in[4];
  const float* bout2 = (const float*)d_in[5];
  const float* wout3 = (const float*)d_in[6];
  const float* bout3 = (const float*)d_in[7];
  const float* win1  = (const float*)d_in[8];
  const float* bin1  = (const float*)d_in[9];
  const float* win2  = (const float*)d_in[10];
  const float* bin2  = (const float*)d_in[11];
  const float* win3  = (const float*)d_in[12];
  const float* bin3  = (const float*)d_in[13];
  float* out = (float*)d_out;

  char* p = (char*)d_ws;
  auto alloc = [&](size_t bytes) { char* r = p; p += (bytes + 255) & ~(size_t)255; return r; };
  int* rpA   = (int*)alloc((size_t)(NN + 1) * 4);
  int* rpB   = (int*)alloc((size_t)(NN + 1) * 4);
  int* colA  = (int*)alloc((size_t)(EE + 16) * 4);
  int* colB  = (int*)alloc((size_t)(EE + 16) * 4);
  float* dinvA = (float*)alloc((size_t)NN * 4);
  float* dinvB = (float*)alloc((size_t)NN * 4);
  int* bCnt  = (int*)alloc((size_t)2 * NB * 4);
  int* bOff  = (int*)alloc((size_t)2 * (NB + 1) * 4);
  int* bCur  = (int*)alloc((size_t)2 * NB * 4);
  unsigned short* wt0 = (unsigned short*)alloc((size_t)192 * 256 * 2);
  unsigned short* wt1 = (unsigned short*)alloc((size_t)192 * 256 * 2);
  unsigned short* wt2 = (unsigned short*)alloc((size_t)192 * 192 * 2);
  unsigned short* wt3 = (unsigned short*)alloc((size_t)192 * 192 * 2);
  unsigned short* wt4 = (unsigned short*)alloc((size_t)192 * 192 * 2);
  unsigned short* wt5 = (unsigned short*)alloc((size_t)192 * 192 * 2);
  unsigned short* Xb = (unsigned short*)alloc((size_t)MPAD * 256 * 2);
  unsigned short* Z0 = (unsigned short*)alloc((size_t)NN * 192 * 2);
  unsigned short* Z1 = (unsigned short*)alloc((size_t)NN * 192 * 2);
  unsigned short* T0 = (unsigned short*)alloc((size_t)NN * 128 * 2);
  unsigned short* T1 = (unsigned short*)alloc((size_t)NN * 128 * 2);
  unsigned short* H0 = (unsigned short*)alloc((size_t)MPAD * 192 * 2);   // pad rows: poison, never read as output
  unsigned short* H1 = (unsigned short*)alloc((size_t)MPAD * 192 * 2);

  unsigned* binA = (unsigned*)Z0;   // alias: bins dead before Z written
  unsigned* binB = (unsigned*)Z1;

  // ---- weight pre-pack + x cast + graph build ----
  k_pack<<<dim3(192, 6), 256, 0, stream>>>(wout1, win1, wout2, win2, wout3, win3,
                                           wt0, wt1, wt2, wt3, wt4, wt5);
  k_xcast<<<MPAD / 8, 256, 0, stream>>>(x, Xb);
  hipMemsetAsync(bCnt, 0, (size_t)2 * NB * 4, stream);
  k_hist<<<391, 256, 0, stream>>>(ei, bCnt);
  k_bscan<<<2, 512, 0, stream>>>(bCnt, bOff, bCur);
  k_scatter<<<391, 256, 0, stream>>>(ei, bCur, binA, binB);
  k_build<<<dim3(NB, 2), 256, 0, stream>>>(binA, binB, bOff, rpA, rpB, colA, colB, dinvA, dinvB);

  dim3 gGemm(196, 2);     // 4 tiles/block (proven sweet spot in R3/R4 A/B)
  dim3 gProp(12500, 2);   // 4 nodes (waves) per block

  // ---- layer 1 (K=256, bf16 x shared by both encoders) ----
  k_gemm<256><<<gGemm, 256, 0, stream>>>(Xb, Xb, wt0, wt1, dinvA, dinvB, Z0, Z1);
  k_prop1<<<gProp, 256, 0, stream>>>(Z0, Z1, T0, T1, rpA, rpB, colA, colB, dinvA, dinvB);
  k_combine<false><<<gProp, 256, 0, stream>>>(Z0, Z1, T0, T1, H0, H1, nullptr, bout1, bin1,
                                              rpA, rpB, colA, colB, dinvA, dinvB);
  // ---- layer 2 (K=192) ----
  k_gemm<192><<<gGemm, 256, 0, stream>>>(H0, H1, wt2, wt3, dinvA, dinvB, Z0, Z1);
  k_prop1<<<gProp, 256, 0, stream>>>(Z0, Z1, T0, T1, rpA, rpB, colA, colB, dinvA, dinvB);
  k_combine<false><<<gProp, 256, 0, stream>>>(Z0, Z1, T0, T1, H0, H1, nullptr, bout2, bin2,
                                              rpA, rpB, colA, colB, dinvA, dinvB);
  // ---- layer 3 (K=192, writes fp32 d_out) ----
  k_gemm<192><<<gGemm, 256, 0, stream>>>(H0, H1, wt4, wt5, dinvA, dinvB, Z0, Z1);
  k_prop1<<<gProp, 256, 0, stream>>>(Z0, Z1, T0, T1, rpA, rpB, colA, colB, dinvA, dinvB);
  k_combine<true><<<gProp, 256, 0, stream>>>(Z0, Z1, T0, T1, H0, H1, out, bout3, bin3,
                                             rpA, rpB, colA, colB, dinvA, dinvB);
}